// Round 7
// baseline (13702.887 us; speedup 1.0000x reference)
//
#include <hip/hip_runtime.h>

#define Tn 512
#define Bn 64
#define Nn 1024
#define Hn 512

typedef __attribute__((ext_vector_type(8))) short short8;
typedef __attribute__((ext_vector_type(4))) float f32x4;
typedef __attribute__((ext_vector_type(4))) int int4v;

__device__ __forceinline__ unsigned short f2bf_hi(float x) {
  unsigned u = __builtin_bit_cast(unsigned, x);
  unsigned r = u + 0x7FFFu + ((u >> 16) & 1u);  // RNE
  return (unsigned short)(r >> 16);
}
__device__ __forceinline__ float bf2f(unsigned short b) {
  unsigned u = ((unsigned)b) << 16;
  return __builtin_bit_cast(float, u);
}
__device__ __forceinline__ float tanh_fast(float x) {
  const float e = __expf(2.f * x);
  return 1.f - 2.f / (e + 1.f);
}

// Frag-major H layout (shorts): idx = (t*2+dir)*32768 + kt*2048 + m*512 + g2*128 + bi*8 + e
//   where within-dir col k = kt*32 + g2*8 + e, batch b = m*16 + bi.

// ---------------------------------------------------------------------------
// k0: SP[b][j] = sum_i s[b][i] * W1[j][i]  + b1[j]
// ---------------------------------------------------------------------------
__global__ __launch_bounds__(256) void k0_sproj(const float* __restrict__ s,
    const float* __restrict__ W1, const float* __restrict__ b1,
    float* __restrict__ SP) {
  const int b = blockIdx.x;
  const int tid = threadIdx.x;
  __shared__ float sl[Nn];
  for (int i = tid; i < Nn; i += 256) sl[i] = s[(size_t)b * Nn + i];
  __syncthreads();
#pragma unroll
  for (int qq = 0; qq < 4; ++qq) {
    const int j = qq * 256 + tid;
    const float* w = W1 + (size_t)j * (2 * Nn);
    float acc = 0.f;
    for (int i = 0; i < Nn; i += 4) {
      const float4 wv = *(const float4*)(w + i);
      acc += sl[i] * wv.x + sl[i + 1] * wv.y + sl[i + 2] * wv.z + sl[i + 3] * wv.w;
    }
    SP[(size_t)b * Nn + j] = acc + b1[j];
  }
}

// ---------------------------------------------------------------------------
// k1_mfma: XW = X @ Wcat^T + bias (row-major f32 out)  (UNCHANGED)
// ---------------------------------------------------------------------------
#define LDA 40
__global__ __launch_bounds__(256) void k1_mfma(const float* __restrict__ X,
    const float* __restrict__ Wf, const float* __restrict__ Wb,
    const float* __restrict__ bif, const float* __restrict__ bib,
    float* __restrict__ XW) {
  __shared__ __align__(16) unsigned short Ahi[128 * LDA];
  __shared__ __align__(16) unsigned short Alo[128 * LDA];
  __shared__ __align__(16) unsigned short Bhi[128 * LDA];
  __shared__ __align__(16) unsigned short Blo[128 * LDA];
  const int tid = threadIdx.x;
  const int n0 = blockIdx.x * 128;
  const int m0 = blockIdx.y * 128;
  const int lane = tid & 63;
  const int w = tid >> 6;
  const int mw = (w >> 1) * 64, nw = (w & 1) * 64;
  const int l15 = lane & 15, l4 = lane >> 4;

  const float* bsrc;
  const float* bias_base;
  if (n0 < 512) { bsrc = Wf + (size_t)n0 * Nn; bias_base = bif + n0; }
  else          { bsrc = Wb + (size_t)(n0 - 512) * Nn; bias_base = bib + (n0 - 512); }

  const int srow = tid >> 1, scol = (tid & 1) * 16;
  const float* ag = X + (size_t)(m0 + srow) * Nn + scol;
  const float* bg = bsrc + (size_t)srow * Nn + scol;

  f32x4 acc[4][4];
#pragma unroll
  for (int i = 0; i < 4; ++i)
#pragma unroll
    for (int j = 0; j < 4; ++j) acc[i][j] = (f32x4){0.f, 0.f, 0.f, 0.f};

  for (int kt = 0; kt < 32; ++kt) {
    const int k0 = kt * 32;
    float4 av[4], bv[4];
#pragma unroll
    for (int c = 0; c < 4; ++c) {
      av[c] = *(const float4*)(ag + k0 + c * 4);
      bv[c] = *(const float4*)(bg + k0 + c * 4);
    }
    __syncthreads();
#pragma unroll
    for (int c = 0; c < 4; ++c) {
      const float a4[4] = {av[c].x, av[c].y, av[c].z, av[c].w};
      const float b4[4] = {bv[c].x, bv[c].y, bv[c].z, bv[c].w};
      ushort4 ah, al, bh, bl;
      unsigned short* ahp = (unsigned short*)&ah;
      unsigned short* alp = (unsigned short*)&al;
      unsigned short* bhp = (unsigned short*)&bh;
      unsigned short* blp = (unsigned short*)&bl;
#pragma unroll
      for (int e = 0; e < 4; ++e) {
        const unsigned short h = f2bf_hi(a4[e]);
        ahp[e] = h; alp[e] = f2bf_hi(a4[e] - bf2f(h));
        const unsigned short g = f2bf_hi(b4[e]);
        bhp[e] = g; blp[e] = f2bf_hi(b4[e] - bf2f(g));
      }
      const int off = srow * LDA + scol + c * 4;
      *(ushort4*)&Ahi[off] = ah; *(ushort4*)&Alo[off] = al;
      *(ushort4*)&Bhi[off] = bh; *(ushort4*)&Blo[off] = bl;
    }
    __syncthreads();
    short8 afh[4], afl[4];
#pragma unroll
    for (int mi = 0; mi < 4; ++mi) {
      const int off = (mw + mi * 16 + l15) * LDA + l4 * 8;
      afh[mi] = *(const short8*)&Ahi[off];
      afl[mi] = *(const short8*)&Alo[off];
    }
#pragma unroll
    for (int ni = 0; ni < 4; ++ni) {
      const int off = (nw + ni * 16 + l15) * LDA + l4 * 8;
      const short8 bfh = *(const short8*)&Bhi[off];
      const short8 bfl = *(const short8*)&Blo[off];
#pragma unroll
      for (int mi = 0; mi < 4; ++mi) {
        acc[mi][ni] = __builtin_amdgcn_mfma_f32_16x16x32_bf16(afh[mi], bfh, acc[mi][ni], 0, 0, 0);
        acc[mi][ni] = __builtin_amdgcn_mfma_f32_16x16x32_bf16(afh[mi], bfl, acc[mi][ni], 0, 0, 0);
        acc[mi][ni] = __builtin_amdgcn_mfma_f32_16x16x32_bf16(afl[mi], bfh, acc[mi][ni], 0, 0, 0);
      }
    }
  }
#pragma unroll
  for (int ni = 0; ni < 4; ++ni) {
    const int col = n0 + nw + ni * 16 + l15;
    const float bias = bias_base[nw + ni * 16 + l15];
#pragma unroll
    for (int mi = 0; mi < 4; ++mi) {
      const int row = m0 + mw + mi * 16 + l4 * 4;
#pragma unroll
      for (int reg = 0; reg < 4; ++reg)
        XW[(size_t)(row + reg) * Nn + col] = acc[mi][ni][reg] + bias;
    }
  }
}

// ---------------------------------------------------------------------------
// k2: batch-partitioned bidirectional scan. 8 WGs = 2 dir x 4 batch-groups,
//   1024 thr (16 waves). The RNN recursion is independent per batch row, so
//   each WG owns its 16 sequences end-to-end: NO cross-WG sync/flags/fences.
//   Wave w owns out-cols [w*32,w*32+32): Whh hi/lo B-frags resident in VGPRs
//   (256) for all 512 steps. h frags double-buffered in LDS (64 KB); one
//   barrier per step. MFMA-pipe-bound: 1536 MFMA/step/CU.
// ---------------------------------------------------------------------------
__global__ __launch_bounds__(1024, 1) void k2_scan(
    const float* __restrict__ XW,
    const float* __restrict__ Whh_f, const float* __restrict__ Whh_b,
    const float* __restrict__ bhh_f, const float* __restrict__ bhh_b,
    unsigned short* __restrict__ HFhi, unsigned short* __restrict__ HFlo) {
  const int wg = blockIdx.x;
  const int dir = wg >> 2;
  const int mg = wg & 3;
  const int tid = threadIdx.x;
  const int lane = tid & 63;
  const int w = tid >> 6;          // wave 0..15 -> out-col block
  const int l15 = lane & 15, l4 = lane >> 4;
  __shared__ __align__(16) unsigned short AhB[2][16 * 512];
  __shared__ __align__(16) unsigned short AlB[2][16 * 512];
  const float* Whh = dir ? Whh_b : Whh_f;
  const float* bhh = dir ? bhh_b : bhh_f;

  // --- Whh B-frags in VGPRs (once): wave w cols w*32 + ni*16 + l15 ---
  short8 Bh[2][16], Bl[2][16];
#pragma unroll
  for (int ni = 0; ni < 2; ++ni) {
    const float* wr = Whh + (size_t)(w * 32 + ni * 16 + l15) * Hn;
#pragma unroll
    for (int kt = 0; kt < 16; ++kt) {
      const float4 w0 = *(const float4*)(wr + kt * 32 + l4 * 8);
      const float4 w1 = *(const float4*)(wr + kt * 32 + l4 * 8 + 4);
      const float wf[8] = {w0.x, w0.y, w0.z, w0.w, w1.x, w1.y, w1.z, w1.w};
      union { unsigned short u[8]; short8 v; } hh, ll;
#pragma unroll
      for (int e = 0; e < 8; ++e) {
        const unsigned short h = f2bf_hi(wf[e]);
        hh.u[e] = h; ll.u[e] = f2bf_hi(wf[e] - bf2f(h));
      }
      Bh[ni][kt] = hh.v; Bl[ni][kt] = ll.v;
    }
  }
  const float bhc0 = bhh[w * 32 + l15];
  const float bhc1 = bhh[w * 32 + 16 + l15];
  const int aoff = l4 * 128 + l15 * 8;   // lane's A-frag offset within a granule
  // epilogue LDS indices (wave writes only its own granule kt=w)
  const int ew0 = w * 512 + (l15 >> 3) * 128 + (l15 & 7);        // ni=0, +bi*8
  const int ew1 = w * 512 + (2 + (l15 >> 3)) * 128 + (l15 & 7);  // ni=1, +bi*8

  int p = 0;
  for (int t = 0; t < Tn; ++t) {
    const int trow = dir ? (Tn - 1 - t) : t;
    // XW loads (independent; compiler overlaps with MFMA phase)
    float xw0[4], xw1[4];
#pragma unroll
    for (int reg = 0; reg < 4; ++reg) {
      const size_t rb = ((size_t)trow * Bn + mg * 16 + l4 * 4 + reg) * Nn +
                        dir * 512 + w * 32 + l15;
      xw0[reg] = XW[rb];
      xw1[reg] = XW[rb + 16];
    }
    f32x4 a00 = {0.f, 0.f, 0.f, 0.f}, a01 = a00, a02 = a00;
    f32x4 a10 = a00, a11 = a00, a12 = a00;
    if (t > 0) {
      const unsigned short* ah = AhB[p];
      const unsigned short* al = AlB[p];
#pragma unroll
      for (int kt = 0; kt < 16; ++kt) {
        const short8 fh = *(const short8*)&ah[kt * 512 + aoff];
        const short8 fl = *(const short8*)&al[kt * 512 + aoff];
        a00 = __builtin_amdgcn_mfma_f32_16x16x32_bf16(fh, Bh[0][kt], a00, 0, 0, 0);
        a01 = __builtin_amdgcn_mfma_f32_16x16x32_bf16(fh, Bl[0][kt], a01, 0, 0, 0);
        a02 = __builtin_amdgcn_mfma_f32_16x16x32_bf16(fl, Bh[0][kt], a02, 0, 0, 0);
        a10 = __builtin_amdgcn_mfma_f32_16x16x32_bf16(fh, Bh[1][kt], a10, 0, 0, 0);
        a11 = __builtin_amdgcn_mfma_f32_16x16x32_bf16(fh, Bl[1][kt], a11, 0, 0, 0);
        a12 = __builtin_amdgcn_mfma_f32_16x16x32_bf16(fl, Bh[1][kt], a12, 0, 0, 0);
      }
    }
    // epilogue: h = tanh(acc + xw + bhh) -> frag-layout LDS (buffer p^1)
    unsigned short* dh = AhB[p ^ 1];
    unsigned short* dl = AlB[p ^ 1];
#pragma unroll
    for (int reg = 0; reg < 4; ++reg) {
      const int bi8 = (l4 * 4 + reg) * 8;
      {
        const float pre = a00[reg] + a01[reg] + a02[reg] + xw0[reg] + bhc0;
        const float h = tanh_fast(pre);
        const unsigned short hi = f2bf_hi(h);
        dh[ew0 + bi8] = hi;
        dl[ew0 + bi8] = f2bf_hi(h - bf2f(hi));
      }
      {
        const float pre = a10[reg] + a11[reg] + a12[reg] + xw1[reg] + bhc1;
        const float h = tanh_fast(pre);
        const unsigned short hi = f2bf_hi(h);
        dh[ew1 + bi8] = hi;
        dl[ew1 + bi8] = f2bf_hi(h - bf2f(hi));
      }
    }
    // copy-out granule kt=w to global frag-major layout.  The wave reads only
    // its OWN writes (same-wave ds ordering) -- no barrier needed before this.
    {
      const size_t gb = (size_t)(trow * 2 + dir) * 32768 + (size_t)w * 2048 +
                        (size_t)mg * 512 + (size_t)lane * 8;
      *(int4v*)(HFhi + gb) = *(const int4v*)&dh[w * 512 + lane * 8];
      *(int4v*)(HFlo + gb) = *(const int4v*)&dl[w * 512 + lane * 8];
    }
    __syncthreads();  // h(t) frags visible to all waves; buffers swap
    p ^= 1;
  }
}

// ---------------------------------------------------------------------------
// k3_mfma: EP[m] += sum_j W2[j]*tanh(sum_k H[m][k]*W1[j][N+k] + SP[b][j])
//   (UNCHANGED -- frag-major A reads)
// ---------------------------------------------------------------------------
__global__ __launch_bounds__(256) void k3_mfma(
    const unsigned short* __restrict__ Hhi, const unsigned short* __restrict__ Hlo,
    const float* __restrict__ W1, const float* __restrict__ SP,
    const float* __restrict__ W2, float* __restrict__ EP) {
  __shared__ __align__(16) unsigned short Ahi[128 * LDA];
  __shared__ __align__(16) unsigned short Alo[128 * LDA];
  __shared__ __align__(16) unsigned short Bhi[128 * LDA];
  __shared__ __align__(16) unsigned short Blo[128 * LDA];
  __shared__ __align__(16) float SPs[64 * 128];
  const int tid = threadIdx.x;
  const int n0 = blockIdx.x * 128;
  const int m0 = blockIdx.y * 128;
  const int lane = tid & 63;
  const int w = tid >> 6;
  const int mw = (w >> 1) * 64, nw = (w & 1) * 64;
  const int l15 = lane & 15, l4 = lane >> 4;

  {
    const int r64 = tid >> 2, c0 = (tid & 3) * 32;
    const float* sps = SP + (size_t)r64 * Nn + n0 + c0;
    float* spd = &SPs[r64 * 128 + c0];
#pragma unroll
    for (int c = 0; c < 8; ++c) *(float4*)(spd + c * 4) = *(const float4*)(sps + c * 4);
  }

  const int srow = tid >> 1, scol = (tid & 1) * 16;
  const int tb = m0 + srow;
  const int t3 = tb >> 6, b3 = tb & 63;
  const size_t abase = (size_t)t3 * 65536 + (size_t)(b3 >> 4) * 512 + (size_t)(b3 & 15) * 8
                     + (size_t)(scol >> 3) * 128;
  const float* bg = W1 + (size_t)(n0 + srow) * (2 * Nn) + Nn + scol;

  f32x4 acc[4][4];
#pragma unroll
  for (int i = 0; i < 4; ++i)
#pragma unroll
    for (int j = 0; j < 4; ++j) acc[i][j] = (f32x4){0.f, 0.f, 0.f, 0.f};

  for (int kt = 0; kt < 32; ++kt) {
    const int k0 = kt * 32;
    const size_t gidx = abase + (size_t)(kt >> 4) * 32768 + (size_t)(kt & 15) * 2048;
    const short8 avh0 = *(const short8*)(Hhi + gidx);
    const short8 avh1 = *(const short8*)(Hhi + gidx + 128);
    const short8 avl0 = *(const short8*)(Hlo + gidx);
    const short8 avl1 = *(const short8*)(Hlo + gidx + 128);
    float4 bv0 = *(const float4*)(bg + k0);
    float4 bv1 = *(const float4*)(bg + k0 + 4);
    float4 bv2 = *(const float4*)(bg + k0 + 8);
    float4 bv3 = *(const float4*)(bg + k0 + 12);
    __syncthreads();
    {
      const int off = srow * LDA + scol;
      *(short8*)&Ahi[off] = avh0; *(short8*)&Ahi[off + 8] = avh1;
      *(short8*)&Alo[off] = avl0; *(short8*)&Alo[off + 8] = avl1;
      const float b16[16] = {bv0.x, bv0.y, bv0.z, bv0.w, bv1.x, bv1.y, bv1.z, bv1.w,
                             bv2.x, bv2.y, bv2.z, bv2.w, bv3.x, bv3.y, bv3.z, bv3.w};
      union { unsigned short u[8]; short8 v; } bh0, bl0, bh1, bl1;
#pragma unroll
      for (int e = 0; e < 8; ++e) {
        unsigned short g = f2bf_hi(b16[e]);
        bh0.u[e] = g; bl0.u[e] = f2bf_hi(b16[e] - bf2f(g));
        g = f2bf_hi(b16[e + 8]);
        bh1.u[e] = g; bl1.u[e] = f2bf_hi(b16[e + 8] - bf2f(g));
      }
      *(short8*)&Bhi[off] = bh0.v; *(short8*)&Bhi[off + 8] = bh1.v;
      *(short8*)&Blo[off] = bl0.v; *(short8*)&Blo[off + 8] = bl1.v;
    }
    __syncthreads();
    short8 afh[4], afl[4];
#pragma unroll
    for (int mi = 0; mi < 4; ++mi) {
      const int off = (mw + mi * 16 + l15) * LDA + l4 * 8;
      afh[mi] = *(const short8*)&Ahi[off];
      afl[mi] = *(const short8*)&Alo[off];
    }
#pragma unroll
    for (int ni = 0; ni < 4; ++ni) {
      const int off = (nw + ni * 16 + l15) * LDA + l4 * 8;
      const short8 bfh = *(const short8*)&Bhi[off];
      const short8 bfl = *(const short8*)&Blo[off];
#pragma unroll
      for (int mi = 0; mi < 4; ++mi) {
        acc[mi][ni] = __builtin_amdgcn_mfma_f32_16x16x32_bf16(afh[mi], bfh, acc[mi][ni], 0, 0, 0);
        acc[mi][ni] = __builtin_amdgcn_mfma_f32_16x16x32_bf16(afh[mi], bfl, acc[mi][ni], 0, 0, 0);
        acc[mi][ni] = __builtin_amdgcn_mfma_f32_16x16x32_bf16(afl[mi], bfh, acc[mi][ni], 0, 0, 0);
      }
    }
  }
  float rs[4][4];
#pragma unroll
  for (int mi = 0; mi < 4; ++mi)
#pragma unroll
    for (int reg = 0; reg < 4; ++reg) rs[mi][reg] = 0.f;
#pragma unroll
  for (int ni = 0; ni < 4; ++ni) {
    const int col_l = nw + ni * 16 + l15;
    const float w2v = W2[n0 + col_l];
#pragma unroll
    for (int mi = 0; mi < 4; ++mi) {
      const int rl = mw + mi * 16 + l4 * 4;
#pragma unroll
      for (int reg = 0; reg < 4; ++reg) {
        const int b64 = (rl + reg) & 63;
        const float u = tanhf(acc[mi][ni][reg] + SPs[b64 * 128 + col_l]);
        rs[mi][reg] += u * w2v;
      }
    }
  }
#pragma unroll
  for (int mi = 0; mi < 4; ++mi)
#pragma unroll
    for (int reg = 0; reg < 4; ++reg) {
      float v = rs[mi][reg];
#pragma unroll
      for (int msk = 1; msk < 16; msk <<= 1) v += __shfl_xor(v, msk);
      if (l15 == 0)
        atomicAdd(EP + m0 + mw + mi * 16 + l4 * 4 + reg, v);
    }
}

// ---------------------------------------------------------------------------
// k4: e = tanh(EP + b2); softmax over t (per b)
// ---------------------------------------------------------------------------
__global__ __launch_bounds__(256) void k4_softmax(const float* __restrict__ EP,
    const float* __restrict__ b2, float* __restrict__ AA) {
  const int b = blockIdx.x;
  const int tid = threadIdx.x;
  __shared__ float rbuf[256];
  const float b2v = b2[0];
  const float v0 = tanhf(EP[(size_t)tid * Bn + b] + b2v);
  const float v1 = tanhf(EP[(size_t)(tid + 256) * Bn + b] + b2v);
  rbuf[tid] = fmaxf(v0, v1);
  __syncthreads();
  for (int off = 128; off > 0; off >>= 1) {
    if (tid < off) rbuf[tid] = fmaxf(rbuf[tid], rbuf[tid + off]);
    __syncthreads();
  }
  const float M = rbuf[0];
  __syncthreads();
  const float e0 = expf(v0 - M);
  const float e1 = expf(v1 - M);
  rbuf[tid] = e0 + e1;
  __syncthreads();
  for (int off = 128; off > 0; off >>= 1) {
    if (tid < off) rbuf[tid] = rbuf[tid] + rbuf[tid + off];
    __syncthreads();
  }
  const float S = rbuf[0];
  AA[(size_t)tid * Bn + b] = e0 / S;
  AA[(size_t)(tid + 256) * Bn + b] = e1 / S;
}

// ---------------------------------------------------------------------------
// k5: out[b][n] = sum_t AA[t][b]*(hi+lo), frag-major reads (UNCHANGED)
// ---------------------------------------------------------------------------
__global__ __launch_bounds__(256) void k5_out(const float* __restrict__ AA,
    const unsigned short* __restrict__ Hhi, const unsigned short* __restrict__ Hlo,
    float* __restrict__ out) {
  const int tid = threadIdx.x;
  const int bi = tid & 15;
  const int ns = tid >> 4;
  const int mb = blockIdx.x;
  const int b = mb * 16 + bi;
  const int n4 = blockIdx.y * 64 + ns * 4;
  const int p = n4;
  const size_t base = (size_t)(p >> 9) * 32768 + (size_t)((p & 511) >> 5) * 2048 +
                      (size_t)mb * 512 + (size_t)((p & 31) >> 3) * 128 +
                      (size_t)bi * 8 + (p & 7);
  float o0 = 0.f, o1 = 0.f, o2 = 0.f, o3 = 0.f;
  for (int t = 0; t < Tn; ++t) {
    const float a = AA[(size_t)t * Bn + b];
    const size_t idx = (size_t)t * 65536 + base;
    const ushort4 hi = *(const ushort4*)(Hhi + idx);
    const ushort4 lo = *(const ushort4*)(Hlo + idx);
    o0 += a * (bf2f(hi.x) + bf2f(lo.x));
    o1 += a * (bf2f(hi.y) + bf2f(lo.y));
    o2 += a * (bf2f(hi.z) + bf2f(lo.z));
    o3 += a * (bf2f(hi.w) + bf2f(lo.w));
  }
  float* op = out + (size_t)b * Nn + n4;
  op[0] = o0; op[1] = o1; op[2] = o2; op[3] = o3;
}

// ---------------------------------------------------------------------------
extern "C" void kernel_launch(void* const* d_in, const int* in_sizes, int n_in,
                              void* d_out, int out_size, void* d_ws, size_t ws_size,
                              hipStream_t stream) {
  const float* s     = (const float*)d_in[0];
  const float* x     = (const float*)d_in[1];
  const float* Wih_f = (const float*)d_in[2];
  const float* Whh_f = (const float*)d_in[3];
  const float* bih_f = (const float*)d_in[4];
  const float* bhh_f = (const float*)d_in[5];
  const float* Wih_b = (const float*)d_in[6];
  const float* Whh_b = (const float*)d_in[7];
  const float* bih_b = (const float*)d_in[8];
  const float* bhh_b = (const float*)d_in[9];
  const float* W1    = (const float*)d_in[10];
  const float* b1    = (const float*)d_in[11];
  const float* W2    = (const float*)d_in[12];
  const float* b2    = (const float*)d_in[13];
  float* out = (float*)d_out;

  float* XW = (float*)d_ws;                                  // 134.2 MB f32
  unsigned short* Hhi = (unsigned short*)(XW + 33554432ULL); // 67.1 MB u16 (frag-major)
  unsigned short* Hlo = Hhi + 33554432ULL;                   // 67.1 MB u16
  float* SP = (float*)(Hlo + 33554432ULL);                   // 65536 f32
  float* EP = SP + 65536ULL;                                 // 32768 f32
  float* AA = EP + 32768ULL;                                 // 32768 f32
  const size_t need = 33554432ULL * 4 + 33554432ULL * 2 * 2 +
                      (65536ULL + 32768 + 32768) * 4;
  if (ws_size < need) return;  // workspace too small: fail visibly

  hipMemsetAsync(EP, 0, 32768 * sizeof(float), stream);

  k0_sproj<<<dim3(64), 256, 0, stream>>>(s, W1, b1, SP);
  k1_mfma<<<dim3(8, 256), 256, 0, stream>>>(x, Wih_f, Wih_b, bih_f, bih_b, XW);
  k2_scan<<<dim3(8), 1024, 0, stream>>>(XW, Whh_f, Whh_b, bhh_f, bhh_b, Hhi, Hlo);
  k3_mfma<<<dim3(8, 256), 256, 0, stream>>>(Hhi, Hlo, W1, SP, W2, EP);
  k4_softmax<<<dim3(64), 256, 0, stream>>>(EP, b2, AA);
  k5_out<<<dim3(4, 16), 256, 0, stream>>>(AA, Hhi, Hlo, out);
}

// Round 8
// 3230.859 us; speedup vs baseline: 4.2413x; 4.2413x over previous
//
#include <hip/hip_runtime.h>

#define Tn 512
#define Bn 64
#define Nn 1024
#define Hn 512

typedef __attribute__((ext_vector_type(8))) short short8;
typedef __attribute__((ext_vector_type(4))) float f32x4;
typedef __attribute__((ext_vector_type(4))) int int4v;

__device__ __forceinline__ unsigned short f2bf_hi(float x) {
  unsigned u = __builtin_bit_cast(unsigned, x);
  unsigned r = u + 0x7FFFu + ((u >> 16) & 1u);  // RNE
  return (unsigned short)(r >> 16);
}
__device__ __forceinline__ float bf2f(unsigned short b) {
  unsigned u = ((unsigned)b) << 16;
  return __builtin_bit_cast(float, u);
}

// Frag-major H layout (shorts): idx = (t*2+dir)*32768 + kt*2048 + m*512 + g2*128 + bi*8 + e
//   where within-dir col k = kt*32 + g2*8 + e, batch b = m*16 + bi.

// ---------------------------------------------------------------------------
// k0: SP[b][j] = sum_i s[b][i] * W1[j][i]  + b1[j]
// ---------------------------------------------------------------------------
__global__ __launch_bounds__(256) void k0_sproj(const float* __restrict__ s,
    const float* __restrict__ W1, const float* __restrict__ b1,
    float* __restrict__ SP) {
  const int b = blockIdx.x;
  const int tid = threadIdx.x;
  __shared__ float sl[Nn];
  for (int i = tid; i < Nn; i += 256) sl[i] = s[(size_t)b * Nn + i];
  __syncthreads();
#pragma unroll
  for (int qq = 0; qq < 4; ++qq) {
    const int j = qq * 256 + tid;
    const float* w = W1 + (size_t)j * (2 * Nn);
    float acc = 0.f;
    for (int i = 0; i < Nn; i += 4) {
      const float4 wv = *(const float4*)(w + i);
      acc += sl[i] * wv.x + sl[i + 1] * wv.y + sl[i + 2] * wv.z + sl[i + 3] * wv.w;
    }
    SP[(size_t)b * Nn + j] = acc + b1[j];
  }
}

// ---------------------------------------------------------------------------
// k1_mfma: XW = X @ Wcat^T + bias (row-major f32 out)  (UNCHANGED from R6)
// ---------------------------------------------------------------------------
#define LDA 40
__global__ __launch_bounds__(256) void k1_mfma(const float* __restrict__ X,
    const float* __restrict__ Wf, const float* __restrict__ Wb,
    const float* __restrict__ bif, const float* __restrict__ bib,
    float* __restrict__ XW) {
  __shared__ __align__(16) unsigned short Ahi[128 * LDA];
  __shared__ __align__(16) unsigned short Alo[128 * LDA];
  __shared__ __align__(16) unsigned short Bhi[128 * LDA];
  __shared__ __align__(16) unsigned short Blo[128 * LDA];
  const int tid = threadIdx.x;
  const int n0 = blockIdx.x * 128;
  const int m0 = blockIdx.y * 128;
  const int lane = tid & 63;
  const int w = tid >> 6;
  const int mw = (w >> 1) * 64, nw = (w & 1) * 64;
  const int l15 = lane & 15, l4 = lane >> 4;

  const float* bsrc;
  const float* bias_base;
  if (n0 < 512) { bsrc = Wf + (size_t)n0 * Nn; bias_base = bif + n0; }
  else          { bsrc = Wb + (size_t)(n0 - 512) * Nn; bias_base = bib + (n0 - 512); }

  const int srow = tid >> 1, scol = (tid & 1) * 16;
  const float* ag = X + (size_t)(m0 + srow) * Nn + scol;
  const float* bg = bsrc + (size_t)srow * Nn + scol;

  f32x4 acc[4][4];
#pragma unroll
  for (int i = 0; i < 4; ++i)
#pragma unroll
    for (int j = 0; j < 4; ++j) acc[i][j] = (f32x4){0.f, 0.f, 0.f, 0.f};

  for (int kt = 0; kt < 32; ++kt) {
    const int k0 = kt * 32;
    float4 av[4], bv[4];
#pragma unroll
    for (int c = 0; c < 4; ++c) {
      av[c] = *(const float4*)(ag + k0 + c * 4);
      bv[c] = *(const float4*)(bg + k0 + c * 4);
    }
    __syncthreads();
#pragma unroll
    for (int c = 0; c < 4; ++c) {
      const float a4[4] = {av[c].x, av[c].y, av[c].z, av[c].w};
      const float b4[4] = {bv[c].x, bv[c].y, bv[c].z, bv[c].w};
      ushort4 ah, al, bh, bl;
      unsigned short* ahp = (unsigned short*)&ah;
      unsigned short* alp = (unsigned short*)&al;
      unsigned short* bhp = (unsigned short*)&bh;
      unsigned short* blp = (unsigned short*)&bl;
#pragma unroll
      for (int e = 0; e < 4; ++e) {
        const unsigned short h = f2bf_hi(a4[e]);
        ahp[e] = h; alp[e] = f2bf_hi(a4[e] - bf2f(h));
        const unsigned short g = f2bf_hi(b4[e]);
        bhp[e] = g; blp[e] = f2bf_hi(b4[e] - bf2f(g));
      }
      const int off = srow * LDA + scol + c * 4;
      *(ushort4*)&Ahi[off] = ah; *(ushort4*)&Alo[off] = al;
      *(ushort4*)&Bhi[off] = bh; *(ushort4*)&Blo[off] = bl;
    }
    __syncthreads();
    short8 afh[4], afl[4];
#pragma unroll
    for (int mi = 0; mi < 4; ++mi) {
      const int off = (mw + mi * 16 + l15) * LDA + l4 * 8;
      afh[mi] = *(const short8*)&Ahi[off];
      afl[mi] = *(const short8*)&Alo[off];
    }
#pragma unroll
    for (int ni = 0; ni < 4; ++ni) {
      const int off = (nw + ni * 16 + l15) * LDA + l4 * 8;
      const short8 bfh = *(const short8*)&Bhi[off];
      const short8 bfl = *(const short8*)&Blo[off];
#pragma unroll
      for (int mi = 0; mi < 4; ++mi) {
        acc[mi][ni] = __builtin_amdgcn_mfma_f32_16x16x32_bf16(afh[mi], bfh, acc[mi][ni], 0, 0, 0);
        acc[mi][ni] = __builtin_amdgcn_mfma_f32_16x16x32_bf16(afh[mi], bfl, acc[mi][ni], 0, 0, 0);
        acc[mi][ni] = __builtin_amdgcn_mfma_f32_16x16x32_bf16(afl[mi], bfh, acc[mi][ni], 0, 0, 0);
      }
    }
  }
#pragma unroll
  for (int ni = 0; ni < 4; ++ni) {
    const int col = n0 + nw + ni * 16 + l15;
    const float bias = bias_base[nw + ni * 16 + l15];
#pragma unroll
    for (int mi = 0; mi < 4; ++mi) {
      const int row = m0 + mw + mi * 16 + l4 * 4;
#pragma unroll
      for (int reg = 0; reg < 4; ++reg)
        XW[(size_t)(row + reg) * Nn + col] = acc[mi][ni][reg] + bias;
    }
  }
}

// ---------------------------------------------------------------------------
// k2: R6 structure (32 WGs = 2 dir x 16 kt-regions, 512 thr, B-frags in VGPR,
//   frag-major h in LLC, chunked vmcnt(8) consumer pipeline) with the sync
//   chain de-fattened:
//     - per-WAVE flags: each wave drains its own stores (wave-local vmcnt(0))
//       and publishes immediately -- no full-WG barrier before visibility
//     - ONLY wave 0 polls (R6: all 256 waves chip-wide hammered 2 cachelines
//       with s_sleep-quantized acquire loads); tight spin, 8B load covers 2
//       flags/lane (128 flags), barrier releases the other waves
//     - trailing barrier dropped (poll-release barrier of t+1 fences LDS)
// ---------------------------------------------------------------------------
#define WAITV8 do { asm volatile("s_waitcnt vmcnt(8)" ::: "memory"); __builtin_amdgcn_sched_barrier(0); } while (0)
#define WAITV0 do { asm volatile("s_waitcnt vmcnt(0)" ::: "memory"); __builtin_amdgcn_sched_barrier(0); } while (0)
#define K2_LD(dh, dl, kt) do { \
    const unsigned short* _ph = pbh + (size_t)(kt) * 2048; \
    const unsigned short* _pl = pbl + (size_t)(kt) * 2048; \
    asm volatile("global_load_dwordx4 %0, %1, off sc0 sc1" : "=v"(dh) : "v"(_ph)); \
    asm volatile("global_load_dwordx4 %0, %1, off sc0 sc1" : "=v"(dl) : "v"(_pl)); \
  } while (0)
#define K2_MM(xh, xl, kt) do { \
    const short8 _a = __builtin_bit_cast(short8, xh); \
    const short8 _c = __builtin_bit_cast(short8, xl); \
    a0 = __builtin_amdgcn_mfma_f32_16x16x32_bf16(_a, Bh[kt], a0, 0, 0, 0); \
    a1 = __builtin_amdgcn_mfma_f32_16x16x32_bf16(_a, Bl[kt], a1, 0, 0, 0); \
    a2 = __builtin_amdgcn_mfma_f32_16x16x32_bf16(_c, Bh[kt], a2, 0, 0, 0); \
  } while (0)

__global__ __launch_bounds__(512, 1) void k2_scan_mfma(
    const float* __restrict__ XW,
    const float* __restrict__ Whh_f, const float* __restrict__ Whh_b,
    const float* __restrict__ bhh_f, const float* __restrict__ bhh_b,
    unsigned short* __restrict__ HFhi, unsigned short* __restrict__ HFlo,
    int* __restrict__ FL) {
  const int wg = blockIdx.x;
  const int dir = wg >> 4;
  const int rg = wg & 15;  // kt-region this WG produces
  const int tid = threadIdx.x;
  const int lane = tid & 63;
  const int w = tid >> 6;
  const int m = w & 3;     // batch-tile
  const int cg = w >> 2;   // col-group within WG (0/1)
  const int l15 = lane & 15, l4 = lane >> 4;
  __shared__ __align__(16) unsigned short PKhi[2048];
  __shared__ __align__(16) unsigned short PKlo[2048];

  const float* Whh = dir ? Whh_b : Whh_f;
  const float* bhh = dir ? bhh_b : bhh_f;
  const int ocol = rg * 32 + cg * 16 + l15;  // within-dir output col (0..511)

  // --- Whh B-frags in VGPRs (once): 128 VGPRs/wave, fits at 8 waves/CU ---
  short8 Bh[16], Bl[16];
  {
    const float* wr = Whh + (size_t)ocol * Hn;
#pragma unroll
    for (int kt = 0; kt < 16; ++kt) {
      const float4 w0 = *(const float4*)(wr + kt * 32 + l4 * 8);
      const float4 w1 = *(const float4*)(wr + kt * 32 + l4 * 8 + 4);
      const float wf[8] = {w0.x, w0.y, w0.z, w0.w, w1.x, w1.y, w1.z, w1.w};
      union { unsigned short u[8]; short8 v; } hh, ll;
#pragma unroll
      for (int e = 0; e < 8; ++e) {
        const unsigned short h = f2bf_hi(wf[e]);
        hh.u[e] = h; ll.u[e] = f2bf_hi(wf[e] - bf2f(h));
      }
      Bh[kt] = hh.v; Bl[kt] = ll.v;
    }
  }
  const float bhh_c = bhh[ocol];
  const int g2p = cg * 2 + (l15 >> 3);
  const int ep = l15 & 7;

  for (int t = 0; t < Tn; ++t) {
    const int trow = dir ? (Tn - 1 - t) : t;
    // XW prefetch via asm (issued before poll; drained by WAITV0 below)
    float xw0, xw1, xw2, xw3;
    {
      const float* xp = XW + ((size_t)trow * Bn + m * 16 + l4 * 4) * Nn + dir * 512 + ocol;
      const float* x0 = xp;             const float* x1 = xp + Nn;
      const float* x2 = xp + 2 * Nn;    const float* x3 = xp + 3 * Nn;
      asm volatile("global_load_dword %0, %1, off" : "=v"(xw0) : "v"(x0));
      asm volatile("global_load_dword %0, %1, off" : "=v"(xw1) : "v"(x1));
      asm volatile("global_load_dword %0, %1, off" : "=v"(xw2) : "v"(x2));
      asm volatile("global_load_dword %0, %1, off" : "=v"(xw3) : "v"(x3));
    }

    f32x4 a0 = {0.f, 0.f, 0.f, 0.f}, a1 = a0, a2 = a0;
    if (t > 0) {
      if (w == 0) {  // wave 0 only: tight spin, 2 flags per lane (128 total)
        const unsigned long long* fp = (const unsigned long long*)(
            FL + (size_t)(((dir << 9) | (t - 1))) * 128);
        while (true) {
          const unsigned long long v = __hip_atomic_load(
              fp + lane, __ATOMIC_RELAXED, __HIP_MEMORY_SCOPE_AGENT);
          if (__all(v == 0x0000000100000001ULL)) break;
        }
      }
      __syncthreads();  // release: flags observed happen-before; sc0sc1 loads
      asm volatile("" ::: "memory");  // read LLC directly -> no inv needed
      const int hprow = dir ? (Tn - t) : (t - 1);
      const unsigned short* pbh =
          HFhi + (size_t)(hprow * 2 + dir) * 32768 + m * 512 + lane * 8;
      const unsigned short* pbl =
          HFlo + (size_t)(hprow * 2 + dir) * 32768 + m * 512 + lane * 8;
      int4v Ph[4], Pl[4], Qh[4], Ql[4];
      K2_LD(Ph[0], Pl[0], 0);  K2_LD(Ph[1], Pl[1], 1);
      K2_LD(Ph[2], Pl[2], 2);  K2_LD(Ph[3], Pl[3], 3);
      K2_LD(Qh[0], Ql[0], 4);  K2_LD(Qh[1], Ql[1], 5);
      K2_LD(Qh[2], Ql[2], 6);  K2_LD(Qh[3], Ql[3], 7);
      WAITV8;
      K2_MM(Ph[0], Pl[0], 0);  K2_MM(Ph[1], Pl[1], 1);
      K2_MM(Ph[2], Pl[2], 2);  K2_MM(Ph[3], Pl[3], 3);
      K2_LD(Ph[0], Pl[0], 8);  K2_LD(Ph[1], Pl[1], 9);
      K2_LD(Ph[2], Pl[2], 10); K2_LD(Ph[3], Pl[3], 11);
      WAITV8;
      K2_MM(Qh[0], Ql[0], 4);  K2_MM(Qh[1], Ql[1], 5);
      K2_MM(Qh[2], Ql[2], 6);  K2_MM(Qh[3], Ql[3], 7);
      K2_LD(Qh[0], Ql[0], 12); K2_LD(Qh[1], Ql[1], 13);
      K2_LD(Qh[2], Ql[2], 14); K2_LD(Qh[3], Ql[3], 15);
      WAITV8;
      K2_MM(Ph[0], Pl[0], 8);  K2_MM(Ph[1], Pl[1], 9);
      K2_MM(Ph[2], Pl[2], 10); K2_MM(Ph[3], Pl[3], 11);
      WAITV0;
      K2_MM(Qh[0], Ql[0], 12); K2_MM(Qh[1], Ql[1], 13);
      K2_MM(Qh[2], Ql[2], 14); K2_MM(Qh[3], Ql[3], 15);
    }
    WAITV0;  // ensure xw regs landed (no-op when t>0)

    // epilogue: h = tanh(acc + xw + bhh); pack hi/lo into LDS in frag order
#pragma unroll
    for (int reg = 0; reg < 4; ++reg) {
      const float xwv = (reg == 0) ? xw0 : (reg == 1) ? xw1 : (reg == 2) ? xw2 : xw3;
      const float pre = a0[reg] + a1[reg] + a2[reg] + xwv + bhh_c;
      const float h = tanhf(pre);
      const unsigned short hi = f2bf_hi(h);
      const unsigned short lo = f2bf_hi(h - bf2f(hi));
      const int idx = m * 512 + g2p * 128 + (l4 * 4 + reg) * 8 + ep;
      PKhi[idx] = hi;
      PKlo[idx] = lo;
    }
    __syncthreads();  // pack complete (cross-wave) before copy-out reads
    {  // 512 threads store 16B each: hi region (tid<256) / lo region
      const int half = tid >> 8;
      const int i = tid & 255;
      unsigned short* dst = (half ? HFlo : HFhi) +
          (size_t)(trow * 2 + dir) * 32768 + (size_t)rg * 2048 + (size_t)i * 8;
      const unsigned short* src = (half ? PKlo : PKhi) + i * 8;
      const int4v v = *(const int4v*)src;
      asm volatile("global_store_dwordx4 %0, %1, off sc0 sc1" :: "v"(dst), "v"(v) : "memory");
    }
    // per-wave: drain own stores (vmcnt is wave-local), publish own flag.
    asm volatile("s_waitcnt vmcnt(0)" ::: "memory");
    if (lane == 0)
      __hip_atomic_store(FL + (size_t)(((dir << 9) | t)) * 128 + rg * 8 + w, 1,
                         __ATOMIC_RELAXED, __HIP_MEMORY_SCOPE_AGENT);
    // no trailing barrier: t+1's poll-release barrier fences PK reuse
  }
}

// ---------------------------------------------------------------------------
// k3_mfma: EP[m] += sum_j W2[j]*tanh(sum_k H[m][k]*W1[j][N+k] + SP[b][j])
//   (UNCHANGED from R6 -- frag-major A reads)
// ---------------------------------------------------------------------------
__global__ __launch_bounds__(256) void k3_mfma(
    const unsigned short* __restrict__ Hhi, const unsigned short* __restrict__ Hlo,
    const float* __restrict__ W1, const float* __restrict__ SP,
    const float* __restrict__ W2, float* __restrict__ EP) {
  __shared__ __align__(16) unsigned short Ahi[128 * LDA];
  __shared__ __align__(16) unsigned short Alo[128 * LDA];
  __shared__ __align__(16) unsigned short Bhi[128 * LDA];
  __shared__ __align__(16) unsigned short Blo[128 * LDA];
  __shared__ __align__(16) float SPs[64 * 128];
  const int tid = threadIdx.x;
  const int n0 = blockIdx.x * 128;
  const int m0 = blockIdx.y * 128;
  const int lane = tid & 63;
  const int w = tid >> 6;
  const int mw = (w >> 1) * 64, nw = (w & 1) * 64;
  const int l15 = lane & 15, l4 = lane >> 4;

  {
    const int r64 = tid >> 2, c0 = (tid & 3) * 32;
    const float* sps = SP + (size_t)r64 * Nn + n0 + c0;
    float* spd = &SPs[r64 * 128 + c0];
#pragma unroll
    for (int c = 0; c < 8; ++c) *(float4*)(spd + c * 4) = *(const float4*)(sps + c * 4);
  }

  const int srow = tid >> 1, scol = (tid & 1) * 16;
  const int tb = m0 + srow;
  const int t3 = tb >> 6, b3 = tb & 63;
  const size_t abase = (size_t)t3 * 65536 + (size_t)(b3 >> 4) * 512 + (size_t)(b3 & 15) * 8
                     + (size_t)(scol >> 3) * 128;
  const float* bg = W1 + (size_t)(n0 + srow) * (2 * Nn) + Nn + scol;

  f32x4 acc[4][4];
#pragma unroll
  for (int i = 0; i < 4; ++i)
#pragma unroll
    for (int j = 0; j < 4; ++j) acc[i][j] = (f32x4){0.f, 0.f, 0.f, 0.f};

  for (int kt = 0; kt < 32; ++kt) {
    const int k0 = kt * 32;
    const size_t gidx = abase + (size_t)(kt >> 4) * 32768 + (size_t)(kt & 15) * 2048;
    const short8 avh0 = *(const short8*)(Hhi + gidx);
    const short8 avh1 = *(const short8*)(Hhi + gidx + 128);
    const short8 avl0 = *(const short8*)(Hlo + gidx);
    const short8 avl1 = *(const short8*)(Hlo + gidx + 128);
    float4 bv0 = *(const float4*)(bg + k0);
    float4 bv1 = *(const float4*)(bg + k0 + 4);
    float4 bv2 = *(const float4*)(bg + k0 + 8);
    float4 bv3 = *(const float4*)(bg + k0 + 12);
    __syncthreads();
    {
      const int off = srow * LDA + scol;
      *(short8*)&Ahi[off] = avh0; *(short8*)&Ahi[off + 8] = avh1;
      *(short8*)&Alo[off] = avl0; *(short8*)&Alo[off + 8] = avl1;
      const float b16[16] = {bv0.x, bv0.y, bv0.z, bv0.w, bv1.x, bv1.y, bv1.z, bv1.w,
                             bv2.x, bv2.y, bv2.z, bv2.w, bv3.x, bv3.y, bv3.z, bv3.w};
      union { unsigned short u[8]; short8 v; } bh0, bl0, bh1, bl1;
#pragma unroll
      for (int e = 0; e < 8; ++e) {
        unsigned short g = f2bf_hi(b16[e]);
        bh0.u[e] = g; bl0.u[e] = f2bf_hi(b16[e] - bf2f(g));
        g = f2bf_hi(b16[e + 8]);
        bh1.u[e] = g; bl1.u[e] = f2bf_hi(b16[e + 8] - bf2f(g));
      }
      *(short8*)&Bhi[off] = bh0.v; *(short8*)&Bhi[off + 8] = bh1.v;
      *(short8*)&Blo[off] = bl0.v; *(short8*)&Blo[off + 8] = bl1.v;
    }
    __syncthreads();
    short8 afh[4], afl[4];
#pragma unroll
    for (int mi = 0; mi < 4; ++mi) {
      const int off = (mw + mi * 16 + l15) * LDA + l4 * 8;
      afh[mi] = *(const short8*)&Ahi[off];
      afl[mi] = *(const short8*)&Alo[off];
    }
#pragma unroll
    for (int ni = 0; ni < 4; ++ni) {
      const int off = (nw + ni * 16 + l15) * LDA + l4 * 8;
      const short8 bfh = *(const short8*)&Bhi[off];
      const short8 bfl = *(const short8*)&Blo[off];
#pragma unroll
      for (int mi = 0; mi < 4; ++mi) {
        acc[mi][ni] = __builtin_amdgcn_mfma_f32_16x16x32_bf16(afh[mi], bfh, acc[mi][ni], 0, 0, 0);
        acc[mi][ni] = __builtin_amdgcn_mfma_f32_16x16x32_bf16(afh[mi], bfl, acc[mi][ni], 0, 0, 0);
        acc[mi][ni] = __builtin_amdgcn_mfma_f32_16x16x32_bf16(afl[mi], bfh, acc[mi][ni], 0, 0, 0);
      }
    }
  }
  float rs[4][4];
#pragma unroll
  for (int mi = 0; mi < 4; ++mi)
#pragma unroll
    for (int reg = 0; reg < 4; ++reg) rs[mi][reg] = 0.f;
#pragma unroll
  for (int ni = 0; ni < 4; ++ni) {
    const int col_l = nw + ni * 16 + l15;
    const float w2v = W2[n0 + col_l];
#pragma unroll
    for (int mi = 0; mi < 4; ++mi) {
      const int rl = mw + mi * 16 + l4 * 4;
#pragma unroll
      for (int reg = 0; reg < 4; ++reg) {
        const int b64 = (rl + reg) & 63;
        const float u = tanhf(acc[mi][ni][reg] + SPs[b64 * 128 + col_l]);
        rs[mi][reg] += u * w2v;
      }
    }
  }
#pragma unroll
  for (int mi = 0; mi < 4; ++mi)
#pragma unroll
    for (int reg = 0; reg < 4; ++reg) {
      float v = rs[mi][reg];
#pragma unroll
      for (int msk = 1; msk < 16; msk <<= 1) v += __shfl_xor(v, msk);
      if (l15 == 0)
        atomicAdd(EP + m0 + mw + mi * 16 + l4 * 4 + reg, v);
    }
}

// ---------------------------------------------------------------------------
// k4: e = tanh(EP + b2); softmax over t (per b)
// ---------------------------------------------------------------------------
__global__ __launch_bounds__(256) void k4_softmax(const float* __restrict__ EP,
    const float* __restrict__ b2, float* __restrict__ AA) {
  const int b = blockIdx.x;
  const int tid = threadIdx.x;
  __shared__ float rbuf[256];
  const float b2v = b2[0];
  const float v0 = tanhf(EP[(size_t)tid * Bn + b] + b2v);
  const float v1 = tanhf(EP[(size_t)(tid + 256) * Bn + b] + b2v);
  rbuf[tid] = fmaxf(v0, v1);
  __syncthreads();
  for (int off = 128; off > 0; off >>= 1) {
    if (tid < off) rbuf[tid] = fmaxf(rbuf[tid], rbuf[tid + off]);
    __syncthreads();
  }
  const float M = rbuf[0];
  __syncthreads();
  const float e0 = expf(v0 - M);
  const float e1 = expf(v1 - M);
  rbuf[tid] = e0 + e1;
  __syncthreads();
  for (int off = 128; off > 0; off >>= 1) {
    if (tid < off) rbuf[tid] = rbuf[tid] + rbuf[tid + off];
    __syncthreads();
  }
  const float S = rbuf[0];
  AA[(size_t)tid * Bn + b] = e0 / S;
  AA[(size_t)(tid + 256) * Bn + b] = e1 / S;
}

// ---------------------------------------------------------------------------
// k5: out[b][n] = sum_t AA[t][b]*(hi+lo), frag-major reads (UNCHANGED)
// ---------------------------------------------------------------------------
__global__ __launch_bounds__(256) void k5_out(const float* __restrict__ AA,
    const unsigned short* __restrict__ Hhi, const unsigned short* __restrict__ Hlo,
    float* __restrict__ out) {
  const int tid = threadIdx.x;
  const int bi = tid & 15;
  const int ns = tid >> 4;
  const int mb = blockIdx.x;
  const int b = mb * 16 + bi;
  const int n4 = blockIdx.y * 64 + ns * 4;
  const int p = n4;
  const size_t base = (size_t)(p >> 9) * 32768 + (size_t)((p & 511) >> 5) * 2048 +
                      (size_t)mb * 512 + (size_t)((p & 31) >> 3) * 128 +
                      (size_t)bi * 8 + (p & 7);
  float o0 = 0.f, o1 = 0.f, o2 = 0.f, o3 = 0.f;
  for (int t = 0; t < Tn; ++t) {
    const float a = AA[(size_t)t * Bn + b];
    const size_t idx = (size_t)t * 65536 + base;
    const ushort4 hi = *(const ushort4*)(Hhi + idx);
    const ushort4 lo = *(const ushort4*)(Hlo + idx);
    o0 += a * (bf2f(hi.x) + bf2f(lo.x));
    o1 += a * (bf2f(hi.y) + bf2f(lo.y));
    o2 += a * (bf2f(hi.z) + bf2f(lo.z));
    o3 += a * (bf2f(hi.w) + bf2f(lo.w));
  }
  float* op = out + (size_t)b * Nn + n4;
  op[0] = o0; op[1] = o1; op[2] = o2; op[3] = o3;
}

// ---------------------------------------------------------------------------
extern "C" void kernel_launch(void* const* d_in, const int* in_sizes, int n_in,
                              void* d_out, int out_size, void* d_ws, size_t ws_size,
                              hipStream_t stream) {
  const float* s     = (const float*)d_in[0];
  const float* x     = (const float*)d_in[1];
  const float* Wih_f = (const float*)d_in[2];
  const float* Whh_f = (const float*)d_in[3];
  const float* bih_f = (const float*)d_in[4];
  const float* bhh_f = (const float*)d_in[5];
  const float* Wih_b = (const float*)d_in[6];
  const float* Whh_b = (const float*)d_in[7];
  const float* bih_b = (const float*)d_in[8];
  const float* bhh_b = (const float*)d_in[9];
  const float* W1    = (const float*)d_in[10];
  const float* b1    = (const float*)d_in[11];
  const float* W2    = (const float*)d_in[12];
  const float* b2    = (const float*)d_in[13];
  float* out = (float*)d_out;

  float* XW = (float*)d_ws;                                  // 134.2 MB f32
  unsigned short* Hhi = (unsigned short*)(XW + 33554432ULL); // 67.1 MB u16 (frag-major)
  unsigned short* Hlo = Hhi + 33554432ULL;                   // 67.1 MB u16
  float* SP = (float*)(Hlo + 33554432ULL);                   // 65536 f32
  float* EP = SP + 65536ULL;                                 // 32768 f32
  float* AA = EP + 32768ULL;                                 // 32768 f32
  int* FL   = (int*)(AA + 32768ULL);                         // 2*512*128 ints (512KB)
  const size_t need = 33554432ULL * 4 + 33554432ULL * 2 * 2 +
                      (65536ULL + 32768 + 32768) * 4 + 131072ULL * 4;
  if (ws_size < need) return;  // workspace too small: fail visibly

  hipMemsetAsync(EP, 0, 32768 * sizeof(float), stream);
  hipMemsetAsync(FL, 0, 131072 * sizeof(int), stream);

  k0_sproj<<<dim3(64), 256, 0, stream>>>(s, W1, b1, SP);
  k1_mfma<<<dim3(8, 256), 256, 0, stream>>>(x, Wih_f, Wih_b, bih_f, bih_b, XW);
  k2_scan_mfma<<<dim3(32), 512, 0, stream>>>(XW, Whh_f, Whh_b, bhh_f, bhh_b, Hhi, Hlo, FL);
  k3_mfma<<<dim3(8, 256), 256, 0, stream>>>(Hhi, Hlo, W1, SP, W2, EP);
  k4_softmax<<<dim3(64), 256, 0, stream>>>(EP, b2, AA);
  k5_out<<<dim3(4, 16), 256, 0, stream>>>(AA, Hhi, Hlo, out);
}